// Round 4
// baseline (385.652 us; speedup 1.0000x reference)
//
#include <hip/hip_runtime.h>
#include <math.h>

#define NB 16
#define NS 4096
#define NH 768
#define NC 64      // chunks per batch
#define CHUNK 64   // rows per chunk

static constexpr float kEps = 1e-9f;

// ---------------------------------------------------------------------------
// k1: per (b,c) block. Each of 4 waves owns 16 rows. For each row:
//   dot(x_row, W) via 12 reg-FMAs + 6-step butterfly; a_j = exp(dot + bias);
//   acc[h] += a_j * x[h] in registers (12 floats/lane, h = i*256 + lane*4 + comp).
// Then LDS-combine 4 waves -> partial[b,c,0:768], and chunk sum of a -> asum.
// ---------------------------------------------------------------------------
__global__ __launch_bounds__(256) void la_k1(
    const float* __restrict__ x, const float* __restrict__ Wp,
    const float* __restrict__ bp,
    float* __restrict__ a, float* __restrict__ partial,
    float* __restrict__ asum)
{
  const int blk  = blockIdx.x;
  const int b    = blk >> 6;   // / NC
  const int c    = blk & 63;   // % NC
  const int t    = threadIdx.x;
  const int w    = t >> 6;
  const int lane = t & 63;
  const float bias = bp[0];

  const float4* W4 = reinterpret_cast<const float4*>(Wp);
  const float4 w0 = W4[lane];
  const float4 w1 = W4[64 + lane];
  const float4 w2 = W4[128 + lane];

  float4 acc0 = {0.f,0.f,0.f,0.f};
  float4 acc1 = {0.f,0.f,0.f,0.f};
  float4 acc2 = {0.f,0.f,0.f,0.f};
  float wsum = 0.f;

  const int row0 = c * CHUNK + w * 16;
  const float* xb = x + (size_t)(b * NS + row0) * NH;

  for (int r = 0; r < 16; ++r) {
    const float4* X4 = reinterpret_cast<const float4*>(xb + (size_t)r * NH);
    const float4 x0 = X4[lane];
    const float4 x1 = X4[64 + lane];
    const float4 x2 = X4[128 + lane];
    float dot = x0.x*w0.x + x0.y*w0.y + x0.z*w0.z + x0.w*w0.w
              + x1.x*w1.x + x1.y*w1.y + x1.z*w1.z + x1.w*w1.w
              + x2.x*w2.x + x2.y*w2.y + x2.z*w2.z + x2.w*w2.w;
    #pragma unroll
    for (int off = 1; off < 64; off <<= 1) dot += __shfl_xor(dot, off);
    const float aj = expf(dot + bias);
    if (lane == 0) a[(size_t)b * NS + row0 + r] = aj;
    wsum += aj;
    acc0.x += aj*x0.x; acc0.y += aj*x0.y; acc0.z += aj*x0.z; acc0.w += aj*x0.w;
    acc1.x += aj*x1.x; acc1.y += aj*x1.y; acc1.z += aj*x1.z; acc1.w += aj*x1.w;
    acc2.x += aj*x2.x; acc2.y += aj*x2.y; acc2.z += aj*x2.z; acc2.w += aj*x2.w;
  }

  __shared__ float lacc[4 * NH];
  __shared__ float lsum[4];
  float4* l4 = reinterpret_cast<float4*>(lacc) + (size_t)w * (NH / 4);
  l4[lane]       = acc0;
  l4[64 + lane]  = acc1;
  l4[128 + lane] = acc2;
  if (lane == 0) lsum[w] = wsum;
  __syncthreads();

  float* pd = partial + (size_t)blk * NH;
  #pragma unroll
  for (int k = 0; k < 3; ++k) {
    const int h = t + k * 256;
    pd[h] = lacc[h] + lacc[NH + h] + lacc[2 * NH + h] + lacc[3 * NH + h];
  }
  if (t == 0) asum[blk] = lsum[0] + lsum[1] + lsum[2] + lsum[3];
}

// ---------------------------------------------------------------------------
// k2a: exclusive scan of the 64 chunk a-sums per batch (one wave per batch).
// ---------------------------------------------------------------------------
__global__ __launch_bounds__(64) void la_k2a(
    const float* __restrict__ asum, float* __restrict__ aoff)
{
  const int b = blockIdx.x;
  const int c = threadIdx.x;
  const float v = asum[b * NC + c];
  float incl = v;
  #pragma unroll
  for (int off = 1; off < 64; off <<= 1) {
    const float n = __shfl_up(incl, off);
    if (c >= off) incl += n;
  }
  aoff[b * NC + c] = incl - v;
}

// ---------------------------------------------------------------------------
// k2b: exclusive scan of partial[b, c, h] over c (Kogge-Stone in LDS),
// in-place. Block = (64 c) x (16 h) = 1024 threads; grid = (48 hg, 16 b).
// ---------------------------------------------------------------------------
__global__ __launch_bounds__(1024) void la_k2b(float* __restrict__ partial)
{
  const int hg = blockIdx.x;
  const int b  = blockIdx.y;
  const int t  = threadIdx.x;
  const int c  = t >> 4;
  const int hh = t & 15;
  const int h  = hg * 16 + hh;
  const size_t idx = (size_t)(b * NC + c) * NH + h;

  const float v = partial[idx];
  __shared__ float lds[NC][16];
  lds[c][hh] = v;
  __syncthreads();
  #pragma unroll
  for (int off = 1; off < 64; off <<= 1) {
    const float n = (c >= off) ? lds[c - off][hh] : 0.f;
    __syncthreads();
    lds[c][hh] += n;
    __syncthreads();
  }
  partial[idx] = lds[c][hh] - v;   // exclusive
}

// ---------------------------------------------------------------------------
// k3: per (b,c) block, 192 threads, one float4 of h per thread. Walk the 64
// rows: out = acc * rcp(den); acc += a_j * x; den is shared across h.
// ---------------------------------------------------------------------------
__global__ __launch_bounds__(192) void la_k3(
    const float* __restrict__ x, const float* __restrict__ a,
    const float* __restrict__ offs /* = scanned partial */,
    const float* __restrict__ aoff,
    float* __restrict__ out)
{
  const int blk = blockIdx.x;
  const int b   = blk >> 6;
  const int c   = blk & 63;
  const int t   = threadIdx.x;
  const int h4  = t * 4;

  __shared__ float la[CHUNK];
  if (t < CHUNK) la[t] = a[(size_t)b * NS + c * CHUNK + t];

  float4 acc = *reinterpret_cast<const float4*>(offs + (size_t)blk * NH + h4);
  const float aofs = aoff[blk];
  __syncthreads();

  const size_t base = ((size_t)b * NS + (size_t)c * CHUNK) * NH + h4;
  const float* xb = x + base;
  float*       ob = out + base;

  float runa = 0.f;
  for (int j = 0; j < CHUNK; ++j) {
    const float aj  = la[j];
    const float den = aofs + runa + kEps;
    const float inv = __builtin_amdgcn_rcpf(den);
    const float4 xv = *reinterpret_cast<const float4*>(xb + (size_t)j * NH);
    float4 o;
    o.x = acc.x * inv; o.y = acc.y * inv; o.z = acc.z * inv; o.w = acc.w * inv;
    *reinterpret_cast<float4*>(ob + (size_t)j * NH) = o;
    acc.x += aj * xv.x; acc.y += aj * xv.y; acc.z += aj * xv.z; acc.w += aj * xv.w;
    runa += aj;
  }
}

// ---------------------------------------------------------------------------
extern "C" void kernel_launch(void* const* d_in, const int* in_sizes, int n_in,
                              void* d_out, int out_size, void* d_ws, size_t ws_size,
                              hipStream_t stream) {
  const float* x  = (const float*)d_in[0];
  const float* Wp = (const float*)d_in[1];
  const float* bp = (const float*)d_in[2];
  float* out = (float*)d_out;

  char* ws = (char*)d_ws;
  float* a       = (float*)(ws);                               // 16*4096*4   = 262144 B
  float* partial = (float*)(ws + 262144);                      // 16*64*768*4 = 3145728 B
  float* asum    = (float*)(ws + 262144 + 3145728);            // 1024*4      = 4096 B
  float* aoff    = (float*)(ws + 262144 + 3145728 + 4096);     // 1024*4      = 4096 B

  la_k1 <<<NB * NC, 256, 0, stream>>>(x, Wp, bp, a, partial, asum);
  la_k2a<<<NB, 64, 0, stream>>>(asum, aoff);
  la_k2b<<<dim3(NH / 16, NB), 1024, 0, stream>>>(partial);
  la_k3 <<<NB * NC, 192, 0, stream>>>(x, a, partial, aoff, out);
}

// Round 7
// 384.330 us; speedup vs baseline: 1.0034x; 1.0034x over previous
//
#include <hip/hip_runtime.h>
#include <math.h>

#define NB 16
#define NS 4096
#define NH 768
#define NC 64      // chunks per batch
#define CHUNK 64   // rows per chunk

static constexpr float kEps = 1e-9f;

// ---------------------------------------------------------------------------
// k1: per (b,c) block, 256 threads = 4 waves, each wave owns 16 rows.
// Per row: dot(x_row, W) via 12 reg-FMAs + 6-step butterfly; a_j = exp(dot+b);
// acc[h] += a_j * x[h] in registers. Row loop unrolled 2x so row r+1's loads
// and dot overlap row r's shfl/exp serial tail. Coalesced a-store at the end.
// ---------------------------------------------------------------------------
__global__ __launch_bounds__(256) void la_k1(
    const float* __restrict__ x, const float* __restrict__ Wp,
    const float* __restrict__ bp,
    float* __restrict__ a, float* __restrict__ partial,
    float* __restrict__ asum)
{
  const int blk  = blockIdx.x;
  const int b    = blk >> 6;   // / NC
  const int c    = blk & 63;   // % NC
  const int t    = threadIdx.x;
  const int w    = t >> 6;
  const int lane = t & 63;
  const float bias = bp[0];

  const float4* W4 = reinterpret_cast<const float4*>(Wp);
  const float4 w0 = W4[lane];
  const float4 w1 = W4[64 + lane];
  const float4 w2 = W4[128 + lane];

  float4 acc0 = {0.f,0.f,0.f,0.f};
  float4 acc1 = {0.f,0.f,0.f,0.f};
  float4 acc2 = {0.f,0.f,0.f,0.f};
  float wsum = 0.f;
  float areg = 0.f;            // lane r keeps a_j of row r (r<16)

  const int row0 = c * CHUNK + w * 16;
  const float* xb = x + (size_t)(b * NS + row0) * NH;

  #pragma unroll 2
  for (int r = 0; r < 16; ++r) {
    const float4* X4 = reinterpret_cast<const float4*>(xb + (size_t)r * NH);
    const float4 x0 = X4[lane];
    const float4 x1 = X4[64 + lane];
    const float4 x2 = X4[128 + lane];
    float dot = x0.x*w0.x + x0.y*w0.y + x0.z*w0.z + x0.w*w0.w
              + x1.x*w1.x + x1.y*w1.y + x1.z*w1.z + x1.w*w1.w
              + x2.x*w2.x + x2.y*w2.y + x2.z*w2.z + x2.w*w2.w;
    #pragma unroll
    for (int off = 1; off < 64; off <<= 1) dot += __shfl_xor(dot, off);
    const float aj = expf(dot + bias);
    if (lane == r) areg = aj;
    wsum += aj;
    acc0.x += aj*x0.x; acc0.y += aj*x0.y; acc0.z += aj*x0.z; acc0.w += aj*x0.w;
    acc1.x += aj*x1.x; acc1.y += aj*x1.y; acc1.z += aj*x1.z; acc1.w += aj*x1.w;
    acc2.x += aj*x2.x; acc2.y += aj*x2.y; acc2.z += aj*x2.z; acc2.w += aj*x2.w;
  }
  if (lane < 16) a[(size_t)b * NS + row0 + lane] = areg;

  __shared__ float lacc[4 * NH];
  __shared__ float lsum[4];
  float4* l4 = reinterpret_cast<float4*>(lacc) + (size_t)w * (NH / 4);
  l4[lane]       = acc0;
  l4[64 + lane]  = acc1;
  l4[128 + lane] = acc2;
  if (lane == 0) lsum[w] = wsum;
  __syncthreads();

  float* pd = partial + (size_t)blk * NH;
  #pragma unroll
  for (int k = 0; k < 3; ++k) {
    const int h = t + k * 256;
    pd[h] = lacc[h] + lacc[NH + h] + lacc[2 * NH + h] + lacc[3 * NH + h];
  }
  if (t == 0) asum[blk] = lsum[0] + lsum[1] + lsum[2] + lsum[3];
}

// ---------------------------------------------------------------------------
// k2: exclusive scan of partial[b, c, h] over c (Kogge-Stone in LDS),
// in-place. Block = (64 c) x (16 h) = 1024 threads; grid = (48 hg, 16 b).
// ---------------------------------------------------------------------------
__global__ __launch_bounds__(1024) void la_k2(float* __restrict__ partial)
{
  const int hg = blockIdx.x;
  const int b  = blockIdx.y;
  const int t  = threadIdx.x;
  const int c  = t >> 4;
  const int hh = t & 15;
  const int h  = hg * 16 + hh;
  const size_t idx = (size_t)(b * NC + c) * NH + h;

  const float v = partial[idx];
  __shared__ float lds[NC][16];
  lds[c][hh] = v;
  __syncthreads();
  #pragma unroll
  for (int off = 1; off < 64; off <<= 1) {
    const float n = (c >= off) ? lds[c - off][hh] : 0.f;
    __syncthreads();
    lds[c][hh] += n;
    __syncthreads();
  }
  partial[idx] = lds[c][hh] - v;   // exclusive
}

// ---------------------------------------------------------------------------
// k3: per (b,c) block, 192 threads, one float4 of h per thread. Computes its
// own denominator offset from asum (<=64 L2-resident floats + butterfly).
// Walks the 64 rows with a one-ahead load pipeline:
//   out = acc * rcp(den); acc += a_j * x.
// ---------------------------------------------------------------------------
__global__ __launch_bounds__(192) void la_k3(
    const float* __restrict__ x, const float* __restrict__ a,
    const float* __restrict__ offs /* = scanned partial */,
    const float* __restrict__ asum,
    float* __restrict__ out)
{
  const int blk = blockIdx.x;
  const int b   = blk >> 6;
  const int c   = blk & 63;
  const int t   = threadIdx.x;
  const int h4  = t * 4;

  __shared__ float la[CHUNK];
  __shared__ float s_aofs;
  if (t < CHUNK) la[t] = a[(size_t)b * NS + c * CHUNK + t];
  if (t < 64) {                       // wave 0: aofs = sum_{cc<c} asum[b,cc]
    float av = (t < c) ? asum[b * NC + t] : 0.f;
    #pragma unroll
    for (int off = 1; off < 64; off <<= 1) av += __shfl_xor(av, off);
    if (t == 0) s_aofs = av;
  }

  float4 acc = *reinterpret_cast<const float4*>(offs + (size_t)blk * NH + h4);
  __syncthreads();
  const float aofs = s_aofs;

  const size_t base = ((size_t)b * NS + (size_t)c * CHUNK) * NH + h4;
  const float* xb = x + base;
  float*       ob = out + base;

  float runa = 0.f;
  float4 xv = *reinterpret_cast<const float4*>(xb);
  #pragma unroll 2
  for (int j = 0; j < CHUNK; ++j) {
    float4 xn = {0.f,0.f,0.f,0.f};
    if (j + 1 < CHUNK)
      xn = *reinterpret_cast<const float4*>(xb + (size_t)(j + 1) * NH);
    const float aj  = la[j];
    const float den = aofs + runa + kEps;
    const float inv = __builtin_amdgcn_rcpf(den);
    float4 o;
    o.x = acc.x * inv; o.y = acc.y * inv; o.z = acc.z * inv; o.w = acc.w * inv;
    *reinterpret_cast<float4*>(ob + (size_t)j * NH) = o;
    acc.x += aj * xv.x; acc.y += aj * xv.y; acc.z += aj * xv.z; acc.w += aj * xv.w;
    runa += aj;
    xv = xn;
  }
}

// ---------------------------------------------------------------------------
extern "C" void kernel_launch(void* const* d_in, const int* in_sizes, int n_in,
                              void* d_out, int out_size, void* d_ws, size_t ws_size,
                              hipStream_t stream) {
  const float* x  = (const float*)d_in[0];
  const float* Wp = (const float*)d_in[1];
  const float* bp = (const float*)d_in[2];
  float* out = (float*)d_out;

  char* ws = (char*)d_ws;
  float* a       = (float*)(ws);                               // 16*4096*4   = 262144 B
  float* partial = (float*)(ws + 262144);                      // 16*64*768*4 = 3145728 B
  float* asum    = (float*)(ws + 262144 + 3145728);            // 1024*4      = 4096 B

  la_k1<<<NB * NC, 256, 0, stream>>>(x, Wp, bp, a, partial, asum);
  la_k2<<<dim3(NH / 16, NB), 1024, 0, stream>>>(partial);
  la_k3<<<NB * NC, 192, 0, stream>>>(x, a, partial, asum, out);
}